// Round 3
// baseline (1662.777 us; speedup 1.0000x reference)
//
#include <hip/hip_runtime.h>
#include <hip/hip_bf16.h>
#include <stdint.h>

#define NN 100000
#define NE 3200000
#define DIM 128
#define HID 512
#define BN_EPS 1e-5f

typedef short short8 __attribute__((ext_vector_type(8)));
typedef float floatx4 __attribute__((ext_vector_type(4)));

__device__ __forceinline__ float bfu2f(unsigned short u) {
    return __uint_as_float(((unsigned int)u) << 16);
}
__device__ __forceinline__ unsigned short f2bfu(float f) {
    union { __hip_bfloat16 h; unsigned short u; } cv;
    cv.h = __float2bfloat16(f);
    return cv.u;
}

// ---------------- init: zero edge counters + BN stat accumulators ----------------
__global__ void k_init(int* __restrict__ cnt, float* __restrict__ stats) {
    int i = blockIdx.x * 256 + threadIdx.x;
    if (i < NN) cnt[i] = 0;
    if (i < 512) stats[i] = 0.f;   // [0..255]=stats1(sum,sumsq), [256..511]=stats2
}

// ---------------- count incoming edges per dst ----------------
__global__ void k_count(const int* __restrict__ dst, int* __restrict__ cnt) {
    int e = blockIdx.x * 256 + threadIdx.x;
    if (e < NE) atomicAdd(&cnt[dst[e]], 1);
}

// ---------------- single-block exclusive scan -> CSR offsets; also dinv ----------------
__global__ __launch_bounds__(1024) void k_scan(const int* __restrict__ cnt, int* __restrict__ offs,
                                               int* __restrict__ cur, float* __restrict__ dinv) {
    __shared__ int wsum[16];
    __shared__ int s_total;
    int t = threadIdx.x;          // 1024 threads = 16 waves
    int lane = t & 63, wid = t >> 6;
    if (t == 0) s_total = 0;
    __syncthreads();
    for (int base = 0; base < NN; base += 1024) {
        int i = base + t;
        int v = (i < NN) ? cnt[i] : 0;
        int incl = v;
        #pragma unroll
        for (int off = 1; off < 64; off <<= 1) {
            int y = __shfl_up(incl, off, 64);
            if (lane >= off) incl += y;
        }
        if (lane == 63) wsum[wid] = incl;
        __syncthreads();
        if (wid == 0) {
            int wv = (lane < 16) ? wsum[lane] : 0;
            int wincl = wv;
            #pragma unroll
            for (int off = 1; off < 16; off <<= 1) {
                int y = __shfl_up(wincl, off, 64);
                if (lane >= off) wincl += y;
            }
            if (lane < 16) wsum[lane] = wincl - wv;   // exclusive wave offsets
        }
        __syncthreads();
        int excl = s_total + wsum[wid] + incl - v;
        if (i < NN) {
            offs[i] = excl;
            cur[i]  = excl;
            dinv[i] = rsqrtf((float)(v + 1));   // deg includes self-loop
        }
        __syncthreads();
        if (t == 1023) s_total = excl + v;
        __syncthreads();
    }
    if (threadIdx.x == 0) offs[NN] = s_total;
}

// ---------------- fill CSR src lists ----------------
__global__ void k_fill(const int* __restrict__ src, const int* __restrict__ dst,
                       int* __restrict__ cur, int* __restrict__ srcs) {
    int e = blockIdx.x * 256 + threadIdx.x;
    if (e < NE) {
        int p = atomicAdd(&cur[dst[e]], 1);
        if ((unsigned)p < NE) srcs[p] = src[e];
    }
}

// ---------------- transpose W (fp32) -> bf16 wt[n][k] (for contiguous MFMA B-frags) ----------------
__global__ void k_wt(const float* __restrict__ W, unsigned short* __restrict__ wt) {
    int i = blockIdx.x * 256 + threadIdx.x;
    if (i < DIM * DIM) {
        int k = i >> 7, n = i & 127;
        wt[n * DIM + k] = f2bfu(W[k * DIM + n]);
    }
}

// ---------------- xw = bf16(x) @ bf16(W) via MFMA 16x16x32; xw bf16 (lives in d_out) ----------------
__global__ __launch_bounds__(256) void k_gemm1(const float* __restrict__ x,
                                               const unsigned short* __restrict__ wt,
                                               unsigned short* __restrict__ xw) {
    int wave = threadIdx.x >> 6;
    int lane = threadIdx.x & 63;
    int row0 = blockIdx.x * 64 + wave * 16;
    int arow = row0 + (lane & 15);
    if (arow >= NN) arow = NN - 1;        // clamp; stores are guarded
    int kbase = (lane >> 4) * 8;
    const float* xr = x + (size_t)arow * DIM;
    short8 afrag[4];
    #pragma unroll
    for (int kt = 0; kt < 4; ++kt) {
        float4 f0 = *(const float4*)(xr + kt * 32 + kbase);
        float4 f1 = *(const float4*)(xr + kt * 32 + kbase + 4);
        short8 a;
        a[0] = (short)f2bfu(f0.x); a[1] = (short)f2bfu(f0.y);
        a[2] = (short)f2bfu(f0.z); a[3] = (short)f2bfu(f0.w);
        a[4] = (short)f2bfu(f1.x); a[5] = (short)f2bfu(f1.y);
        a[6] = (short)f2bfu(f1.z); a[7] = (short)f2bfu(f1.w);
        afrag[kt] = a;                     // A[m=lane&15][k=quad*8+j]
    }
    int crow = row0 + (lane >> 4) * 4;
    #pragma unroll
    for (int ct = 0; ct < 8; ++ct) {
        int ncol = ct * 16 + (lane & 15);
        const short* wr = (const short*)wt + (size_t)ncol * DIM;
        floatx4 acc = {0.f, 0.f, 0.f, 0.f};
        #pragma unroll
        for (int kt = 0; kt < 4; ++kt) {
            short8 bfrag = *(const short8*)(wr + kt * 32 + kbase); // B[k=quad*8+j][n=lane&15]
            acc = __builtin_amdgcn_mfma_f32_16x16x32_bf16(afrag[kt], bfrag, acc, 0, 0, 0);
        }
        #pragma unroll
        for (int i = 0; i < 4; ++i) {
            int r = crow + i;                  // C: row=(lane>>4)*4+reg, col=lane&15
            if (r < NN) xw[(size_t)r * DIM + ct * 16 + (lane & 15)] = f2bfu(acc[i]);
        }
    }
}

// ---------------- per-node wave: u = bf16(x + h), h = sym-norm aggregate + bias ----------------
__global__ __launch_bounds__(256) void k_aggregate(const unsigned int* __restrict__ xw2,
                                                   const int* __restrict__ offs,
                                                   const int* __restrict__ srcs,
                                                   const float* __restrict__ dinv,
                                                   const float* __restrict__ x,
                                                   const float* __restrict__ b,
                                                   unsigned int* __restrict__ u) {
    int node = blockIdx.x * 4 + (threadIdx.x >> 6);
    if (node >= NN) return;
    int lane = threadIdx.x & 63;               // lane handles cols 2*lane, 2*lane+1
    int beg = offs[node], end = offs[node + 1];
    beg = max(0, min(beg, NE));
    end = max(beg, min(end, NE));
    float a0 = 0.f, a1 = 0.f;
    for (int e = beg; e < end; ++e) {
        int s = srcs[e];
        if ((unsigned)s >= NN) s = 0;
        float w = dinv[s];
        unsigned int pw = xw2[(size_t)s * (DIM / 2) + lane];
        a0 = fmaf(w, __uint_as_float(pw << 16), a0);
        a1 = fmaf(w, __uint_as_float(pw & 0xffff0000u), a1);
    }
    float di = dinv[node];
    unsigned int ps = xw2[(size_t)node * (DIM / 2) + lane];
    a0 = di * a0 + di * di * __uint_as_float(ps << 16);
    a1 = di * a1 + di * di * __uint_as_float(ps & 0xffff0000u);
    float2 xv = ((const float2*)x)[(size_t)node * (DIM / 2) + lane];
    float2 bv = ((const float2*)b)[lane];
    float o0 = a0 + bv.x + xv.x;
    float o1 = a1 + bv.y + xv.y;
    unsigned int pk = ((unsigned int)f2bfu(o1) << 16) | (unsigned int)f2bfu(o0);
    u[(size_t)node * (DIM / 2) + lane] = pk;
}

// ---------------- BN1 stats: per-column sum & sumsq of u (bf16) ----------------
__global__ void k_stats(const unsigned int* __restrict__ u2, float* __restrict__ stats) {
    int t = threadIdx.x;            // 256
    int c = t & 63, g = t >> 6;     // uint index c -> bf16 cols 2c, 2c+1
    float s0 = 0.f, q0 = 0.f, s1 = 0.f, q1 = 0.f;
    for (int r = blockIdx.x * 4 + g; r < NN; r += gridDim.x * 4) {
        unsigned int pv = u2[(size_t)r * 64 + c];
        float x0 = __uint_as_float(pv << 16);
        float x1 = __uint_as_float(pv & 0xffff0000u);
        s0 += x0; q0 += x0 * x0; s1 += x1; q1 += x1 * x1;
    }
    __shared__ float A[256], B[256], C[256], D2[256];
    A[t] = s0; B[t] = q0; C[t] = s1; D2[t] = q1;
    __syncthreads();
    if (t < 64) {
        float rs0 = A[t] + A[t + 64] + A[t + 128] + A[t + 192];
        float rq0 = B[t] + B[t + 64] + B[t + 128] + B[t + 192];
        float rs1 = C[t] + C[t + 64] + C[t + 128] + C[t + 192];
        float rq1 = D2[t] + D2[t + 64] + D2[t + 128] + D2[t + 192];
        atomicAdd(&stats[2 * c],           rs0);
        atomicAdd(&stats[2 * c + 1],       rs1);
        atomicAdd(&stats[DIM + 2 * c],     rq0);
        atomicAdd(&stats[DIM + 2 * c + 1], rq1);
    }
}

// ---------------- fused: y1 = BN1(u); t = relu(y1@w1+b1); v = y1 + t@w2+b2 (fp32); BN2 stats ----------------
__global__ __launch_bounds__(512) void k_ff(const unsigned short* __restrict__ u16,
                                            const float* __restrict__ stats1,
                                            const float* __restrict__ gamma,
                                            const float* __restrict__ beta,
                                            const float* __restrict__ w1,
                                            const float* __restrict__ b1,
                                            const float* __restrict__ w2,
                                            const float* __restrict__ b2,
                                            float* __restrict__ v,
                                            float* __restrict__ stats2) {
    __shared__ float sy[8][DIM];     // y1 tile
    __shared__ float st[8][HID];     // hidden tile
    __shared__ float smu[DIM], srs[DIM], sg[DIM], sb[DIM];
    __shared__ float red[512], red2[512];
    int tid = threadIdx.x;           // 512
    if (tid < DIM) {
        float mu  = stats1[tid] * (1.0f / NN);
        float var = stats1[DIM + tid] * (1.0f / NN) - mu * mu;
        smu[tid] = mu;
        srs[tid] = rsqrtf(var + BN_EPS);
        sg[tid] = gamma[tid];
        sb[tid] = beta[tid];
    }
    __syncthreads();
    float b1j = b1[tid];
    int c2 = tid & 127, r2 = tid >> 7;
    float b2c = b2[c2];
    float ssum = 0.f, ssq = 0.f;
    const int ntiles = NN / 8;       // 12500, exact
    for (int tile = blockIdx.x; tile < ntiles; tile += gridDim.x) {
        int row0 = tile * 8;
        for (int idx = tid; idx < 8 * DIM; idx += 512) {
            int r = idx >> 7, c = idx & 127;
            float uval = bfu2f(u16[(size_t)(row0 + r) * DIM + c]);
            sy[r][c] = (uval - smu[c]) * srs[c] * sg[c] + sb[c];
        }
        __syncthreads();
        // GEMM1: thread = hidden unit, 8 rows
        float acc[8] = {0, 0, 0, 0, 0, 0, 0, 0};
        for (int k = 0; k < DIM; ++k) {
            float wv = w1[k * HID + tid];
            #pragma unroll
            for (int r = 0; r < 8; ++r) acc[r] = fmaf(sy[r][k], wv, acc[r]);
        }
        #pragma unroll
        for (int r = 0; r < 8; ++r) st[r][tid] = fmaxf(acc[r] + b1j, 0.f);
        __syncthreads();
        // GEMM2: thread = (row pair r2/r2+4, col c2)
        float a0 = 0.f, a1 = 0.f;
        for (int k = 0; k < HID; ++k) {
            float wv = w2[k * DIM + c2];
            a0 = fmaf(st[r2][k], wv, a0);
            a1 = fmaf(st[r2 + 4][k], wv, a1);
        }
        float v0 = sy[r2][c2]     + a0 + b2c;
        float v1 = sy[r2 + 4][c2] + a1 + b2c;
        v[(size_t)(row0 + r2) * DIM + c2]     = v0;
        v[(size_t)(row0 + r2 + 4) * DIM + c2] = v1;
        ssum += v0 + v1;
        ssq  += v0 * v0 + v1 * v1;
        __syncthreads();
    }
    red[tid] = ssum; red2[tid] = ssq;
    __syncthreads();
    if (tid < 128) {
        atomicAdd(&stats2[tid],       red[tid] + red[tid + 128] + red[tid + 256] + red[tid + 384]);
        atomicAdd(&stats2[DIM + tid], red2[tid] + red2[tid + 128] + red2[tid + 256] + red2[tid + 384]);
    }
}

// ---------------- final BN2 in place on v (fp32, in d_out) ----------------
__global__ void k_final(float* buf, const float* __restrict__ stats2,
                        const float* __restrict__ gamma,
                        const float* __restrict__ beta) {
    __shared__ float ssc[DIM], ssh[DIM];
    int t = threadIdx.x;
    if (t < DIM) {
        float mu  = stats2[t] * (1.0f / NN);
        float var = stats2[DIM + t] * (1.0f / NN) - mu * mu;
        float rsg = rsqrtf(var + BN_EPS) * gamma[t];
        ssc[t] = rsg;
        ssh[t] = beta[t] - mu * rsg;
    }
    __syncthreads();
    const int total = NN * DIM / 4;   // float4s
    float4* b4 = (float4*)buf;
    for (int i = blockIdx.x * blockDim.x + t; i < total; i += gridDim.x * blockDim.x) {
        float4 val = b4[i];
        int c = (i * 4) & (DIM - 1);
        val.x = val.x * ssc[c]     + ssh[c];
        val.y = val.y * ssc[c + 1] + ssh[c + 1];
        val.z = val.z * ssc[c + 2] + ssh[c + 2];
        val.w = val.w * ssc[c + 3] + ssh[c + 3];
        b4[i] = val;
    }
}

extern "C" void kernel_launch(void* const* d_in, const int* in_sizes, int n_in,
                              void* d_out, int out_size, void* d_ws, size_t ws_size,
                              hipStream_t stream) {
    const float* x     = (const float*)d_in[0];
    const int*   ei    = (const int*)d_in[1];
    const float* W     = (const float*)d_in[2];
    const float* b     = (const float*)d_in[3];
    const float* gamma = (const float*)d_in[4];
    const float* beta  = (const float*)d_in[5];
    const float* w1    = (const float*)d_in[6];
    const float* b1    = (const float*)d_in[7];
    const float* w2    = (const float*)d_in[8];
    const float* b2    = (const float*)d_in[9];

    // workspace bump allocator (~27.5 MB), 256B-aligned regions
    char* p = (char*)d_ws;
    auto alloc = [&](size_t bytes) { char* r = p; p += (bytes + 255) & ~(size_t)255; return r; };
    unsigned int*   u     = (unsigned int*)alloc((size_t)NN * DIM * 2);   // u = x + h, bf16 packed
    int*            cnt   = (int*)alloc((size_t)NN * 4);
    int*            offs  = (int*)alloc((size_t)(NN + 1) * 4);
    int*            cur   = (int*)alloc((size_t)NN * 4);
    float*          dinv  = (float*)alloc((size_t)NN * 4);
    unsigned short* wt    = (unsigned short*)alloc((size_t)DIM * DIM * 2);
    float*          stats = (float*)alloc(512 * 4);

    // d_out (51.2 MB fp32) doubles as scratch during the graph phase:
    //   [0, 25.6MB)      xw  (bf16, N*D)
    //   [25.6, 38.4MB)   srcs (int, NE)        — both dead before k_ff writes v
    unsigned short* xw   = (unsigned short*)d_out;
    int*            srcs = (int*)((char*)d_out + (size_t)NN * DIM * 2);
    float*          v    = (float*)d_out;

    const int* esrc = ei;
    const int* edst = ei + NE;

    k_init<<<(NN + 255) / 256, 256, 0, stream>>>(cnt, stats);
    k_count<<<(NE + 255) / 256, 256, 0, stream>>>(edst, cnt);
    k_scan<<<1, 1024, 0, stream>>>(cnt, offs, cur, dinv);
    k_fill<<<(NE + 255) / 256, 256, 0, stream>>>(esrc, edst, cur, srcs);
    k_wt<<<(DIM * DIM + 255) / 256, 256, 0, stream>>>(W, wt);
    k_gemm1<<<(NN + 63) / 64, 256, 0, stream>>>(x, wt, xw);
    k_aggregate<<<(NN + 3) / 4, 256, 0, stream>>>((const unsigned int*)xw, offs, srcs, dinv, x, b, u);
    k_stats<<<512, 256, 0, stream>>>(u, stats);
    k_ff<<<1024, 512, 0, stream>>>((const unsigned short*)u, stats, gamma, beta, w1, b1, w2, b2, v, stats + 256);
    k_final<<<2048, 256, 0, stream>>>((float*)d_out, stats + 256, gamma, beta);
}

// Round 4
// 1103.474 us; speedup vs baseline: 1.5069x; 1.5069x over previous
//
#include <hip/hip_runtime.h>
#include <hip/hip_bf16.h>
#include <stdint.h>

#define NN 100000
#define NE 3200000
#define DIM 128
#define HID 512
#define BN_EPS 1e-5f

typedef short short8 __attribute__((ext_vector_type(8)));
typedef float floatx4 __attribute__((ext_vector_type(4)));

__device__ __forceinline__ float bfu2f(unsigned short u) {
    return __uint_as_float(((unsigned int)u) << 16);
}
__device__ __forceinline__ unsigned short f2bfu(float f) {
    union { __hip_bfloat16 h; unsigned short u; } cv;
    cv.h = __float2bfloat16(f);
    return cv.u;
}

// ---------------- init: zero edge counters + BN stat accumulators ----------------
__global__ void k_init(int* __restrict__ cnt, float* __restrict__ stats) {
    int i = blockIdx.x * 256 + threadIdx.x;
    if (i < NN) cnt[i] = 0;
    if (i < 512) stats[i] = 0.f;   // [0..127]=sum1,[128..255]=sq1,[256..383]=sum2,[384..511]=sq2
}

// ---------------- count incoming edges per dst ----------------
__global__ void k_count(const int* __restrict__ dst, int* __restrict__ cnt) {
    int e = blockIdx.x * 256 + threadIdx.x;
    if (e < NE) atomicAdd(&cnt[dst[e]], 1);
}

// ---------------- single-block exclusive scan -> CSR offsets; also dinv ----------------
__global__ __launch_bounds__(1024) void k_scan(const int* __restrict__ cnt, int* __restrict__ offs,
                                               int* __restrict__ cur, float* __restrict__ dinv) {
    __shared__ int wsum[16];
    __shared__ int s_total;
    int t = threadIdx.x;          // 1024 threads = 16 waves
    int lane = t & 63, wid = t >> 6;
    if (t == 0) s_total = 0;
    __syncthreads();
    for (int base = 0; base < NN; base += 1024) {
        int i = base + t;
        int v = (i < NN) ? cnt[i] : 0;
        int incl = v;
        #pragma unroll
        for (int off = 1; off < 64; off <<= 1) {
            int y = __shfl_up(incl, off, 64);
            if (lane >= off) incl += y;
        }
        if (lane == 63) wsum[wid] = incl;
        __syncthreads();
        if (wid == 0) {
            int wv = (lane < 16) ? wsum[lane] : 0;
            int wincl = wv;
            #pragma unroll
            for (int off = 1; off < 16; off <<= 1) {
                int y = __shfl_up(wincl, off, 64);
                if (lane >= off) wincl += y;
            }
            if (lane < 16) wsum[lane] = wincl - wv;   // exclusive wave offsets
        }
        __syncthreads();
        int excl = s_total + wsum[wid] + incl - v;
        if (i < NN) {
            offs[i] = excl;
            cur[i]  = excl;
            dinv[i] = rsqrtf((float)(v + 1));   // deg includes self-loop
        }
        __syncthreads();
        if (t == 1023) s_total = excl + v;
        __syncthreads();
    }
    if (threadIdx.x == 0) offs[NN] = s_total;
}

// ---------------- fill CSR src lists ----------------
__global__ void k_fill(const int* __restrict__ src, const int* __restrict__ dst,
                       int* __restrict__ cur, int* __restrict__ srcs) {
    int e = blockIdx.x * 256 + threadIdx.x;
    if (e < NE) {
        int p = atomicAdd(&cur[dst[e]], 1);
        if ((unsigned)p < NE) srcs[p] = src[e];
    }
}

// ---------------- transpose W (fp32) -> bf16 wt[n][k] ----------------
__global__ void k_wt(const float* __restrict__ W, unsigned short* __restrict__ wt) {
    int i = blockIdx.x * 256 + threadIdx.x;
    if (i < DIM * DIM) {
        int k = i >> 7, n = i & 127;
        wt[n * DIM + k] = f2bfu(W[k * DIM + n]);
    }
}

// ---------------- prep FF weights: w1t[n=512][k=128], w2t[n=128][k=512] (bf16, transposed) -------
__global__ void k_prep(const float* __restrict__ w1, const float* __restrict__ w2,
                       unsigned short* __restrict__ w1t, unsigned short* __restrict__ w2t) {
    int i = blockIdx.x * 256 + threadIdx.x;
    if (i < HID * DIM) {
        int n1 = i >> 7, k1 = i & 127;           // w1t[n1*128+k1] = w1[k1*512+n1]
        w1t[i] = f2bfu(w1[k1 * HID + n1]);
        int n2 = i & 127, k2 = i >> 7;           // w2t[n2*512+k2] = w2[k2*128+n2]
        w2t[n2 * HID + k2] = f2bfu(w2[k2 * DIM + n2]);
    }
}

// ---------------- xw = bf16(x) @ bf16(W) via MFMA 16x16x32; xw bf16 (lives in d_out) ----------------
__global__ __launch_bounds__(256) void k_gemm1(const float* __restrict__ x,
                                               const unsigned short* __restrict__ wt,
                                               unsigned short* __restrict__ xw) {
    int wave = threadIdx.x >> 6;
    int lane = threadIdx.x & 63;
    int row0 = blockIdx.x * 64 + wave * 16;
    int arow = row0 + (lane & 15);
    if (arow >= NN) arow = NN - 1;        // clamp; stores are guarded
    int kbase = (lane >> 4) * 8;
    const float* xr = x + (size_t)arow * DIM;
    short8 afrag[4];
    #pragma unroll
    for (int kt = 0; kt < 4; ++kt) {
        float4 f0 = *(const float4*)(xr + kt * 32 + kbase);
        float4 f1 = *(const float4*)(xr + kt * 32 + kbase + 4);
        short8 a;
        a[0] = (short)f2bfu(f0.x); a[1] = (short)f2bfu(f0.y);
        a[2] = (short)f2bfu(f0.z); a[3] = (short)f2bfu(f0.w);
        a[4] = (short)f2bfu(f1.x); a[5] = (short)f2bfu(f1.y);
        a[6] = (short)f2bfu(f1.z); a[7] = (short)f2bfu(f1.w);
        afrag[kt] = a;                     // A[m=lane&15][k=quad*8+j]
    }
    int crow = row0 + (lane >> 4) * 4;
    #pragma unroll
    for (int ct = 0; ct < 8; ++ct) {
        int ncol = ct * 16 + (lane & 15);
        const short* wr = (const short*)wt + (size_t)ncol * DIM;
        floatx4 acc = {0.f, 0.f, 0.f, 0.f};
        #pragma unroll
        for (int kt = 0; kt < 4; ++kt) {
            short8 bfrag = *(const short8*)(wr + kt * 32 + kbase); // B[k=quad*8+j][n=lane&15]
            acc = __builtin_amdgcn_mfma_f32_16x16x32_bf16(afrag[kt], bfrag, acc, 0, 0, 0);
        }
        #pragma unroll
        for (int i = 0; i < 4; ++i) {
            int r = crow + i;                  // C: row=(lane>>4)*4+reg, col=lane&15
            if (r < NN) xw[(size_t)r * DIM + ct * 16 + (lane & 15)] = f2bfu(acc[i]);
        }
    }
}

// ---------------- per-node wave: u = bf16(x + h), h = sym-norm aggregate + bias ----------------
__global__ __launch_bounds__(256) void k_aggregate(const unsigned int* __restrict__ xw2,
                                                   const int* __restrict__ offs,
                                                   const int* __restrict__ srcs,
                                                   const float* __restrict__ dinv,
                                                   const float* __restrict__ x,
                                                   const float* __restrict__ b,
                                                   unsigned int* __restrict__ u) {
    int node = blockIdx.x * 4 + (threadIdx.x >> 6);
    if (node >= NN) return;
    int lane = threadIdx.x & 63;               // lane handles cols 2*lane, 2*lane+1
    int beg = offs[node], end = offs[node + 1];
    beg = max(0, min(beg, NE));
    end = max(beg, min(end, NE));
    float a0 = 0.f, a1 = 0.f;
    #pragma unroll 4
    for (int e = beg; e < end; ++e) {
        int s = srcs[e];
        if ((unsigned)s >= NN) s = 0;
        float w = dinv[s];
        unsigned int pw = xw2[(size_t)s * (DIM / 2) + lane];
        a0 = fmaf(w, __uint_as_float(pw << 16), a0);
        a1 = fmaf(w, __uint_as_float(pw & 0xffff0000u), a1);
    }
    float di = dinv[node];
    unsigned int ps = xw2[(size_t)node * (DIM / 2) + lane];
    a0 = di * a0 + di * di * __uint_as_float(ps << 16);
    a1 = di * a1 + di * di * __uint_as_float(ps & 0xffff0000u);
    float2 xv = ((const float2*)x)[(size_t)node * (DIM / 2) + lane];
    float2 bv = ((const float2*)b)[lane];
    float o0 = a0 + bv.x + xv.x;
    float o1 = a1 + bv.y + xv.y;
    unsigned int pk = ((unsigned int)f2bfu(o1) << 16) | (unsigned int)f2bfu(o0);
    u[(size_t)node * (DIM / 2) + lane] = pk;
}

// ---------------- BN1 stats: per-column sum & sumsq of u (bf16) ----------------
__global__ void k_stats(const unsigned int* __restrict__ u2, float* __restrict__ stats) {
    int t = threadIdx.x;            // 256
    int c = t & 63, g = t >> 6;     // uint index c -> bf16 cols 2c, 2c+1
    float s0 = 0.f, q0 = 0.f, s1 = 0.f, q1 = 0.f;
    for (int r = blockIdx.x * 4 + g; r < NN; r += gridDim.x * 4) {
        unsigned int pv = u2[(size_t)r * 64 + c];
        float x0 = __uint_as_float(pv << 16);
        float x1 = __uint_as_float(pv & 0xffff0000u);
        s0 += x0; q0 += x0 * x0; s1 += x1; q1 += x1 * x1;
    }
    __shared__ float A[256], B[256], C[256], D2[256];
    A[t] = s0; B[t] = q0; C[t] = s1; D2[t] = q1;
    __syncthreads();
    if (t < 64) {
        float rs0 = A[t] + A[t + 64] + A[t + 128] + A[t + 192];
        float rq0 = B[t] + B[t + 64] + B[t + 128] + B[t + 192];
        float rs1 = C[t] + C[t + 64] + C[t + 128] + C[t + 192];
        float rq1 = D2[t] + D2[t + 64] + D2[t + 128] + D2[t + 192];
        atomicAdd(&stats[2 * c],           rs0);
        atomicAdd(&stats[2 * c + 1],       rs1);
        atomicAdd(&stats[DIM + 2 * c],     rq0);
        atomicAdd(&stats[DIM + 2 * c + 1], rq1);
    }
}

// ---------------- BN2 stats: per-column sum & sumsq of v (fp32) ----------------
__global__ void k_stats2(const float2* __restrict__ v2, float* __restrict__ stats) {
    int t = threadIdx.x;            // 256
    int c = t & 63, g = t >> 6;     // float2 index c -> cols 2c, 2c+1
    float s0 = 0.f, q0 = 0.f, s1 = 0.f, q1 = 0.f;
    for (int r = blockIdx.x * 4 + g; r < NN; r += gridDim.x * 4) {
        float2 pv = v2[(size_t)r * 64 + c];
        s0 += pv.x; q0 += pv.x * pv.x; s1 += pv.y; q1 += pv.y * pv.y;
    }
    __shared__ float A[256], B[256], C[256], D2[256];
    A[t] = s0; B[t] = q0; C[t] = s1; D2[t] = q1;
    __syncthreads();
    if (t < 64) {
        float rs0 = A[t] + A[t + 64] + A[t + 128] + A[t + 192];
        float rq0 = B[t] + B[t + 64] + B[t + 128] + B[t + 192];
        float rs1 = C[t] + C[t + 64] + C[t + 128] + C[t + 192];
        float rq1 = D2[t] + D2[t + 64] + D2[t + 128] + D2[t + 192];
        atomicAdd(&stats[2 * c],           rs0);
        atomicAdd(&stats[2 * c + 1],       rs1);
        atomicAdd(&stats[DIM + 2 * c],     rq0);
        atomicAdd(&stats[DIM + 2 * c + 1], rq1);
    }
}

// ---------------- MFMA fused FF: y1=BN1(u); v = y1 + relu(y1@w1+b1)@w2 + b2 (fp32 into d_out) -----
// One wave per 16-row strip. gemm1 computed transposed (hT = w1t x y1^T) so the
// hidden C-layout gives each lane 4 consecutive k for a fixed node; C->A transform
// for gemm2 is then 8 b64 writes + 8 b64 reads per chunk (2-way bank alias = free).
__global__ __launch_bounds__(256) void k_ff(const unsigned int* __restrict__ u2,
                                            const float* __restrict__ stats1,
                                            const float* __restrict__ gamma,
                                            const float* __restrict__ beta,
                                            const unsigned short* __restrict__ w1t,
                                            const float* __restrict__ b1,
                                            const unsigned short* __restrict__ w2t,
                                            const float* __restrict__ b2,
                                            float* __restrict__ v) {
    __shared__ __align__(16) float sscale[DIM], sshift[DIM];
    __shared__ __align__(16) unsigned short y1s[4][16 * 136];   // per-wave, pad 8 shorts/row
    __shared__ __align__(16) unsigned int   hbuf[4][16 * 66];   // per-wave, pad 2 uints/row
    int tid = threadIdx.x;
    if (tid < DIM) {
        float mu  = stats1[tid] * (1.0f / NN);
        float var = stats1[DIM + tid] * (1.0f / NN) - mu * mu;
        float sc = rsqrtf(var + BN_EPS) * gamma[tid];
        sscale[tid] = sc;
        sshift[tid] = beta[tid] - mu * sc;
    }
    __syncthreads();
    int wave = tid >> 6, lane = tid & 63;
    int strip = blockIdx.x * 4 + wave;           // 6250 strips of 16 rows, exact
    if (strip >= NN / 16) return;
    int m = lane & 15, q = lane >> 4;
    unsigned short* y1 = &y1s[wave][0];
    unsigned int*   hb = &hbuf[wave][0];

    // phase A: load u rows (bf16 packed), BN1, store y1 to LDS
    {
        int row = strip * 16 + m;
        const uint4* usrc = (const uint4*)(u2 + (size_t)row * 64 + q * 16);
        #pragma unroll
        for (int g = 0; g < 4; ++g) {
            uint4 pv = usrc[g];
            int c0 = q * 32 + g * 8;
            float4 sc0 = *(const float4*)&sscale[c0], sc1 = *(const float4*)&sscale[c0 + 4];
            float4 sh0 = *(const float4*)&sshift[c0], sh1 = *(const float4*)&sshift[c0 + 4];
            float f0 = __uint_as_float(pv.x << 16)         * sc0.x + sh0.x;
            float f1 = __uint_as_float(pv.x & 0xffff0000u) * sc0.y + sh0.y;
            float f2 = __uint_as_float(pv.y << 16)         * sc0.z + sh0.z;
            float f3 = __uint_as_float(pv.y & 0xffff0000u) * sc0.w + sh0.w;
            float f4 = __uint_as_float(pv.z << 16)         * sc1.x + sh1.x;
            float f5 = __uint_as_float(pv.z & 0xffff0000u) * sc1.y + sh1.y;
            float f6 = __uint_as_float(pv.w << 16)         * sc1.z + sh1.z;
            float f7 = __uint_as_float(pv.w & 0xffff0000u) * sc1.w + sh1.w;
            uint4 ov;
            ov.x = ((unsigned int)f2bfu(f1) << 16) | f2bfu(f0);
            ov.y = ((unsigned int)f2bfu(f3) << 16) | f2bfu(f2);
            ov.z = ((unsigned int)f2bfu(f5) << 16) | f2bfu(f4);
            ov.w = ((unsigned int)f2bfu(f7) << 16) | f2bfu(f6);
            *(uint4*)(y1 + m * 136 + c0) = ov;
        }
    }
    // y1 frags (B-operand for gemm1T; lane&15 = node, k contiguous)
    short8 yfrag[4];
    #pragma unroll
    for (int kt = 0; kt < 4; ++kt)
        yfrag[kt] = *(const short8*)(y1 + m * 136 + kt * 32 + q * 8);

    floatx4 acc2[8];
    #pragma unroll
    for (int t = 0; t < 8; ++t) acc2[t] = (floatx4){0.f, 0.f, 0.f, 0.f};

    #pragma unroll
    for (int c = 0; c < 4; ++c) {
        const unsigned short* w1c = w1t + (size_t)(c * 128) * DIM;
        // gemm1T: D(16 hid x 16 node) = w1t_frag x y1_frag
        floatx4 acc1[8];
        #pragma unroll
        for (int t = 0; t < 8; ++t) acc1[t] = (floatx4){0.f, 0.f, 0.f, 0.f};
        #pragma unroll
        for (int kt = 0; kt < 4; ++kt) {
            #pragma unroll
            for (int t = 0; t < 8; ++t) {
                short8 wf = *(const short8*)(w1c + (size_t)(t * 16 + m) * DIM + kt * 32 + q * 8);
                acc1[t] = __builtin_amdgcn_mfma_f32_16x16x32_bf16(wf, yfrag[kt], acc1[t], 0, 0, 0);
            }
        }
        // relu + bias; lane holds h[node=m][hid = t*16 + q*4 + i] -> pack k-block b = t*4+q
        #pragma unroll
        for (int t = 0; t < 8; ++t) {
            float4 bb = *(const float4*)&b1[c * 128 + t * 16 + q * 4];
            float h0 = fmaxf(acc1[t][0] + bb.x, 0.f);
            float h1 = fmaxf(acc1[t][1] + bb.y, 0.f);
            float h2 = fmaxf(acc1[t][2] + bb.z, 0.f);
            float h3 = fmaxf(acc1[t][3] + bb.w, 0.f);
            uint2 hp;
            hp.x = ((unsigned int)f2bfu(h1) << 16) | f2bfu(h0);
            hp.y = ((unsigned int)f2bfu(h3) << 16) | f2bfu(h2);
            *(uint2*)(hb + m * 66 + (t * 4 + q) * 2) = hp;
        }
        // gemm2: A = h frag (node m, k contiguous via hbuf), B = w2t frag
        const unsigned short* w2c = w2t + c * 128;
        #pragma unroll
        for (int kt = 0; kt < 4; ++kt) {
            uint2 p0 = *(const uint2*)(hb + m * 66 + (8 * kt + 2 * q) * 2);
            uint2 p1 = *(const uint2*)(hb + m * 66 + (8 * kt + 2 * q) * 2 + 2);
            union { unsigned int u[4]; short8 s; } hf;
            hf.u[0] = p0.x; hf.u[1] = p0.y; hf.u[2] = p1.x; hf.u[3] = p1.y;
            #pragma unroll
            for (int t = 0; t < 8; ++t) {
                short8 wf = *(const short8*)(w2c + (size_t)(t * 16 + m) * HID + kt * 32 + q * 8);
                acc2[t] = __builtin_amdgcn_mfma_f32_16x16x32_bf16(hf.s, wf, acc2[t], 0, 0, 0);
            }
        }
    }
    // epilogue: C acc2[t]: node = q*4+i, outcol = t*16+m; v = y1 + ff + b2
    #pragma unroll
    for (int t = 0; t < 8; ++t) {
        float b2c = b2[t * 16 + m];
        #pragma unroll
        for (int i = 0; i < 4; ++i) {
            int r = q * 4 + i;
            float y1v = bfu2f(y1[r * 136 + t * 16 + m]);
            v[(size_t)(strip * 16 + r) * DIM + t * 16 + m] = acc2[t][i] + b2c + y1v;
        }
    }
}

// ---------------- final BN2 in place on v (fp32, in d_out) ----------------
__global__ void k_final(float* buf, const float* __restrict__ stats2,
                        const float* __restrict__ gamma,
                        const float* __restrict__ beta) {
    __shared__ float ssc[DIM], ssh[DIM];
    int t = threadIdx.x;
    if (t < DIM) {
        float mu  = stats2[t] * (1.0f / NN);
        float var = stats2[DIM + t] * (1.0f / NN) - mu * mu;
        float rsg = rsqrtf(var + BN_EPS) * gamma[t];
        ssc[t] = rsg;
        ssh[t] = beta[t] - mu * rsg;
    }
    __syncthreads();
    const int total = NN * DIM / 4;   // float4s
    float4* b4 = (float4*)buf;
    for (int i = blockIdx.x * blockDim.x + t; i < total; i += gridDim.x * blockDim.x) {
        float4 val = b4[i];
        int c = (i * 4) & (DIM - 1);
        val.x = val.x * ssc[c]     + ssh[c];
        val.y = val.y * ssc[c + 1] + ssh[c + 1];
        val.z = val.z * ssc[c + 2] + ssh[c + 2];
        val.w = val.w * ssc[c + 3] + ssh[c + 3];
        b4[i] = val;
    }
}

extern "C" void kernel_launch(void* const* d_in, const int* in_sizes, int n_in,
                              void* d_out, int out_size, void* d_ws, size_t ws_size,
                              hipStream_t stream) {
    const float* x     = (const float*)d_in[0];
    const int*   ei    = (const int*)d_in[1];
    const float* W     = (const float*)d_in[2];
    const float* b     = (const float*)d_in[3];
    const float* gamma = (const float*)d_in[4];
    const float* beta  = (const float*)d_in[5];
    const float* w1    = (const float*)d_in[6];
    const float* b1    = (const float*)d_in[7];
    const float* w2    = (const float*)d_in[8];
    const float* b2    = (const float*)d_in[9];

    // workspace bump allocator (~27.8 MB), 256B-aligned regions
    char* p = (char*)d_ws;
    auto alloc = [&](size_t bytes) { char* r = p; p += (bytes + 255) & ~(size_t)255; return r; };
    unsigned int*   u     = (unsigned int*)alloc((size_t)NN * DIM * 2);   // u = x + h, bf16 packed
    int*            cnt   = (int*)alloc((size_t)NN * 4);
    int*            offs  = (int*)alloc((size_t)(NN + 1) * 4);
    int*            cur   = (int*)alloc((size_t)NN * 4);
    float*          dinv  = (float*)alloc((size_t)NN * 4);
    unsigned short* wt    = (unsigned short*)alloc((size_t)DIM * DIM * 2);
    unsigned short* w1t   = (unsigned short*)alloc((size_t)HID * DIM * 2);
    unsigned short* w2t   = (unsigned short*)alloc((size_t)HID * DIM * 2);
    float*          stats = (float*)alloc(512 * 4);

    // d_out (51.2 MB fp32) doubles as scratch during the graph phase:
    //   [0, 25.6MB)      xw  (bf16, N*D)
    //   [25.6, 38.4MB)   srcs (int, NE)        — both dead before k_ff writes v
    unsigned short* xw   = (unsigned short*)d_out;
    int*            srcs = (int*)((char*)d_out + (size_t)NN * DIM * 2);
    float*          v    = (float*)d_out;

    const int* esrc = ei;
    const int* edst = ei + NE;

    k_init<<<(NN + 255) / 256, 256, 0, stream>>>(cnt, stats);
    k_count<<<(NE + 255) / 256, 256, 0, stream>>>(edst, cnt);
    k_scan<<<1, 1024, 0, stream>>>(cnt, offs, cur, dinv);
    k_fill<<<(NE + 255) / 256, 256, 0, stream>>>(esrc, edst, cur, srcs);
    k_wt<<<(DIM * DIM + 255) / 256, 256, 0, stream>>>(W, wt);
    k_prep<<<(HID * DIM + 255) / 256, 256, 0, stream>>>(w1, w2, w1t, w2t);
    k_gemm1<<<(NN + 63) / 64, 256, 0, stream>>>(x, wt, xw);
    k_aggregate<<<(NN + 3) / 4, 256, 0, stream>>>((const unsigned int*)xw, offs, srcs, dinv, x, b, u);
    k_stats<<<512, 256, 0, stream>>>(u, stats);
    k_ff<<<(NN / 16 + 3) / 4, 256, 0, stream>>>(u, stats, gamma, beta, w1t, b1, w2t, b2, v);
    k_stats2<<<512, 256, 0, stream>>>((const float2*)v, stats + 256);
    k_final<<<2048, 256, 0, stream>>>((float*)d_out, stats + 256, gamma, beta);
}

// Round 5
// 894.036 us; speedup vs baseline: 1.8599x; 1.2343x over previous
//
#include <hip/hip_runtime.h>
#include <hip/hip_bf16.h>
#include <stdint.h>

#define NN 100000
#define NE 3200000
#define DIM 128
#define HID 512
#define BN_EPS 1e-5f
#define FILL_GROUPS 128   // k_fill: edge chunks; grid = FILL_GROUPS*8 blocks

typedef short short8 __attribute__((ext_vector_type(8)));
typedef float floatx4 __attribute__((ext_vector_type(4)));

__device__ __forceinline__ float bfu2f(unsigned short u) {
    return __uint_as_float(((unsigned int)u) << 16);
}
__device__ __forceinline__ unsigned short f2bfu(float f) {
    union { __hip_bfloat16 h; unsigned short u; } cv;
    cv.h = __float2bfloat16(f);
    return cv.u;
}

// ---------------- init: zero edge counters + BN stat accumulators ----------------
__global__ void k_init(int* __restrict__ cnt, float* __restrict__ stats) {
    int i = blockIdx.x * 256 + threadIdx.x;
    if (i < NN) cnt[i] = 0;
    if (i < 512) stats[i] = 0.f;   // [0..127]=sum1,[128..255]=sq1,[256..383]=sum2,[384..511]=sq2
}

// ---------------- count incoming edges per dst ----------------
__global__ void k_count(const int* __restrict__ dst, int* __restrict__ cnt) {
    int e = blockIdx.x * 256 + threadIdx.x;
    if (e < NE) atomicAdd(&cnt[dst[e]], 1);
}

// ---------------- scan stage A: per-block (1024-wide) local exclusive scan + block sums + dinv ----
__global__ __launch_bounds__(1024) void k_scanA(const int* __restrict__ cnt, int* __restrict__ offs,
                                                int* __restrict__ bsum, float* __restrict__ dinv) {
    __shared__ int wsum[16];
    int t = threadIdx.x;          // 1024 threads = 16 waves
    int lane = t & 63, wid = t >> 6;
    int i = blockIdx.x * 1024 + t;
    int v = (i < NN) ? cnt[i] : 0;
    int incl = v;
    #pragma unroll
    for (int off = 1; off < 64; off <<= 1) {
        int y = __shfl_up(incl, off, 64);
        if (lane >= off) incl += y;
    }
    if (lane == 63) wsum[wid] = incl;
    __syncthreads();
    if (wid == 0) {
        int wv = (lane < 16) ? wsum[lane] : 0;
        int wincl = wv;
        #pragma unroll
        for (int off = 1; off < 16; off <<= 1) {
            int y = __shfl_up(wincl, off, 64);
            if (lane >= off) wincl += y;
        }
        if (lane < 16) wsum[lane] = wincl - wv;   // exclusive wave offsets
    }
    __syncthreads();
    int excl = wsum[wid] + incl - v;              // block-local exclusive
    if (i < NN) {
        offs[i] = excl;
        dinv[i] = rsqrtf((float)(v + 1));         // deg includes self-loop
    }
    if (t == 1023) bsum[blockIdx.x] = excl + v;   // block total
}

// ---------------- scan stage B: single block scans the 98 block sums ----------------
__global__ __launch_bounds__(128) void k_scanB(int* __restrict__ bsum, int* __restrict__ offs, int nblk) {
    int t = threadIdx.x;   // 128 >= nblk; two waves, use wave 0 only
    if (t < 64) {
        int v = (t < nblk) ? bsum[t] : 0;
        int v2 = (t + 64 < nblk) ? bsum[t + 64] : 0;
        // serial-ish scan over <=128 values in one wave via shfl (64 then fold)
        int incl = v;
        #pragma unroll
        for (int off = 1; off < 64; off <<= 1) {
            int y = __shfl_up(incl, off, 64);
            if (t >= off) incl += y;
        }
        int tot0 = __shfl(incl, 63, 64);
        int incl2 = v2;
        #pragma unroll
        for (int off = 1; off < 64; off <<= 1) {
            int y = __shfl_up(incl2, off, 64);
            if (t >= off) incl2 += y;
        }
        if (t < nblk) bsum[t] = incl - v;                      // exclusive
        if (t + 64 < nblk) bsum[t + 64] = tot0 + incl2 - v2;
        if (t == 63) offs[NN] = tot0 + __shfl(incl2, 63, 64);  // grand total
    }
}

// ---------------- scan stage C: add block bases; init cur ----------------
__global__ void k_scanC(int* __restrict__ offs, const int* __restrict__ bsum, int* __restrict__ cur) {
    int i = blockIdx.x * 256 + threadIdx.x;
    if (i < NN) {
        int o = offs[i] + bsum[i >> 10];
        offs[i] = o;
        cur[i] = o;
    }
}

// ---------------- fill CSR src lists, XCD-range-partitioned ----------------
// block = (group g = blockIdx>>3, range k = blockIdx&7). Block handles edge chunk g,
// but only edges with dst in k-th eighth of nodes. With round-robin block->XCD dispatch,
// each 1.6MB srcs subregion is written by a single XCD -> L2 write combining, ~1x writeback.
__global__ __launch_bounds__(256) void k_fill(const int* __restrict__ src, const int* __restrict__ dst,
                                              int* __restrict__ cur, int* __restrict__ srcs) {
    int k = blockIdx.x & 7;
    int g = blockIdx.x >> 3;
    const int lo = k * (NN / 8), hi = lo + (NN / 8);    // 12500 each, exact
    const int per = NE / FILL_GROUPS;                    // 25000, exact
    int base = g * per;
    for (int e = base + threadIdx.x; e < base + per; e += 256) {
        int d = dst[e];
        if (d >= lo && d < hi) {
            int p = atomicAdd(&cur[d], 1);
            if ((unsigned)p < NE) srcs[p] = src[e];
        }
    }
}

// ---------------- transpose W (fp32) -> bf16 wt[n][k] ----------------
__global__ void k_wt(const float* __restrict__ W, unsigned short* __restrict__ wt) {
    int i = blockIdx.x * 256 + threadIdx.x;
    if (i < DIM * DIM) {
        int k = i >> 7, n = i & 127;
        wt[n * DIM + k] = f2bfu(W[k * DIM + n]);
    }
}

// ---------------- prep FF weights: w1t[n=512][k=128], w2t[n=128][k=512] (bf16, transposed) -------
__global__ void k_prep(const float* __restrict__ w1, const float* __restrict__ w2,
                       unsigned short* __restrict__ w1t, unsigned short* __restrict__ w2t) {
    int i = blockIdx.x * 256 + threadIdx.x;
    if (i < HID * DIM) {
        int n1 = i >> 7, k1 = i & 127;           // w1t[n1*128+k1] = w1[k1*512+n1]
        w1t[i] = f2bfu(w1[k1 * HID + n1]);
        int n2 = i & 127, k2 = i >> 7;           // w2t[n2*512+k2] = w2[k2*128+n2]
        w2t[n2 * HID + k2] = f2bfu(w2[k2 * DIM + n2]);
    }
}

// ---------------- xw = bf16(x) @ bf16(W) via MFMA 16x16x32; xw bf16 (lives in d_out) ----------------
__global__ __launch_bounds__(256) void k_gemm1(const float* __restrict__ x,
                                               const unsigned short* __restrict__ wt,
                                               unsigned short* __restrict__ xw) {
    int wave = threadIdx.x >> 6;
    int lane = threadIdx.x & 63;
    int row0 = blockIdx.x * 64 + wave * 16;
    int arow = row0 + (lane & 15);
    if (arow >= NN) arow = NN - 1;        // clamp; stores are guarded
    int kbase = (lane >> 4) * 8;
    const float* xr = x + (size_t)arow * DIM;
    short8 afrag[4];
    #pragma unroll
    for (int kt = 0; kt < 4; ++kt) {
        float4 f0 = *(const float4*)(xr + kt * 32 + kbase);
        float4 f1 = *(const float4*)(xr + kt * 32 + kbase + 4);
        short8 a;
        a[0] = (short)f2bfu(f0.x); a[1] = (short)f2bfu(f0.y);
        a[2] = (short)f2bfu(f0.z); a[3] = (short)f2bfu(f0.w);
        a[4] = (short)f2bfu(f1.x); a[5] = (short)f2bfu(f1.y);
        a[6] = (short)f2bfu(f1.z); a[7] = (short)f2bfu(f1.w);
        afrag[kt] = a;                     // A[m=lane&15][k=quad*8+j]
    }
    int crow = row0 + (lane >> 4) * 4;
    #pragma unroll
    for (int ct = 0; ct < 8; ++ct) {
        int ncol = ct * 16 + (lane & 15);
        const short* wr = (const short*)wt + (size_t)ncol * DIM;
        floatx4 acc = {0.f, 0.f, 0.f, 0.f};
        #pragma unroll
        for (int kt = 0; kt < 4; ++kt) {
            short8 bfrag = *(const short8*)(wr + kt * 32 + kbase); // B[k=quad*8+j][n=lane&15]
            acc = __builtin_amdgcn_mfma_f32_16x16x32_bf16(afrag[kt], bfrag, acc, 0, 0, 0);
        }
        #pragma unroll
        for (int i = 0; i < 4; ++i) {
            int r = crow + i;                  // C: row=(lane>>4)*4+reg, col=lane&15
            if (r < NN) xw[(size_t)r * DIM + ct * 16 + (lane & 15)] = f2bfu(acc[i]);
        }
    }
}

// ---------------- per-node wave: u = bf16(x + h), h = sym-norm aggregate + bias ----------------
__global__ __launch_bounds__(256) void k_aggregate(const unsigned int* __restrict__ xw2,
                                                   const int* __restrict__ offs,
                                                   const int* __restrict__ srcs,
                                                   const float* __restrict__ dinv,
                                                   const float* __restrict__ x,
                                                   const float* __restrict__ b,
                                                   unsigned int* __restrict__ u) {
    int node = blockIdx.x * 4 + (threadIdx.x >> 6);
    if (node >= NN) return;
    int lane = threadIdx.x & 63;               // lane handles cols 2*lane, 2*lane+1
    int beg = offs[node], end = offs[node + 1];
    beg = max(0, min(beg, NE));
    end = max(beg, min(end, NE));
    float a0 = 0.f, a1 = 0.f;
    #pragma unroll 4
    for (int e = beg; e < end; ++e) {
        int s = srcs[e];
        if ((unsigned)s >= NN) s = 0;
        float w = dinv[s];
        unsigned int pw = xw2[(size_t)s * (DIM / 2) + lane];
        a0 = fmaf(w, __uint_as_float(pw << 16), a0);
        a1 = fmaf(w, __uint_as_float(pw & 0xffff0000u), a1);
    }
    float di = dinv[node];
    unsigned int ps = xw2[(size_t)node * (DIM / 2) + lane];
    a0 = di * a0 + di * di * __uint_as_float(ps << 16);
    a1 = di * a1 + di * di * __uint_as_float(ps & 0xffff0000u);
    float2 xv = ((const float2*)x)[(size_t)node * (DIM / 2) + lane];
    float2 bv = ((const float2*)b)[lane];
    float o0 = a0 + bv.x + xv.x;
    float o1 = a1 + bv.y + xv.y;
    unsigned int pk = ((unsigned int)f2bfu(o1) << 16) | (unsigned int)f2bfu(o0);
    u[(size_t)node * (DIM / 2) + lane] = pk;
}

// ---------------- BN1 stats: per-column sum & sumsq of u (bf16) ----------------
__global__ void k_stats(const unsigned int* __restrict__ u2, float* __restrict__ stats) {
    int t = threadIdx.x;            // 256
    int c = t & 63, g = t >> 6;     // uint index c -> bf16 cols 2c, 2c+1
    float s0 = 0.f, q0 = 0.f, s1 = 0.f, q1 = 0.f;
    for (int r = blockIdx.x * 4 + g; r < NN; r += gridDim.x * 4) {
        unsigned int pv = u2[(size_t)r * 64 + c];
        float x0 = __uint_as_float(pv << 16);
        float x1 = __uint_as_float(pv & 0xffff0000u);
        s0 += x0; q0 += x0 * x0; s1 += x1; q1 += x1 * x1;
    }
    __shared__ float A[256], B[256], C[256], D2[256];
    A[t] = s0; B[t] = q0; C[t] = s1; D2[t] = q1;
    __syncthreads();
    if (t < 64) {
        float rs0 = A[t] + A[t + 64] + A[t + 128] + A[t + 192];
        float rq0 = B[t] + B[t + 64] + B[t + 128] + B[t + 192];
        float rs1 = C[t] + C[t + 64] + C[t + 128] + C[t + 192];
        float rq1 = D2[t] + D2[t + 64] + D2[t + 128] + D2[t + 192];
        atomicAdd(&stats[2 * c],           rs0);
        atomicAdd(&stats[2 * c + 1],       rs1);
        atomicAdd(&stats[DIM + 2 * c],     rq0);
        atomicAdd(&stats[DIM + 2 * c + 1], rq1);
    }
}

// ---------------- BN2 stats: per-column sum & sumsq of v (fp32) ----------------
__global__ void k_stats2(const float2* __restrict__ v2, float* __restrict__ stats) {
    int t = threadIdx.x;            // 256
    int c = t & 63, g = t >> 6;     // float2 index c -> cols 2c, 2c+1
    float s0 = 0.f, q0 = 0.f, s1 = 0.f, q1 = 0.f;
    for (int r = blockIdx.x * 4 + g; r < NN; r += gridDim.x * 4) {
        float2 pv = v2[(size_t)r * 64 + c];
        s0 += pv.x; q0 += pv.x * pv.x; s1 += pv.y; q1 += pv.y * pv.y;
    }
    __shared__ float A[256], B[256], C[256], D2[256];
    A[t] = s0; B[t] = q0; C[t] = s1; D2[t] = q1;
    __syncthreads();
    if (t < 64) {
        float rs0 = A[t] + A[t + 64] + A[t + 128] + A[t + 192];
        float rq0 = B[t] + B[t + 64] + B[t + 128] + B[t + 192];
        float rs1 = C[t] + C[t + 64] + C[t + 128] + C[t + 192];
        float rq1 = D2[t] + D2[t + 64] + D2[t + 128] + D2[t + 192];
        atomicAdd(&stats[2 * c],           rs0);
        atomicAdd(&stats[2 * c + 1],       rs1);
        atomicAdd(&stats[DIM + 2 * c],     rq0);
        atomicAdd(&stats[DIM + 2 * c + 1], rq1);
    }
}

// ---------------- MFMA fused FF: y1=BN1(u); v = y1 + relu(y1@w1+b1)@w2 + b2 (fp32 into d_out) -----
__global__ __launch_bounds__(256) void k_ff(const unsigned int* __restrict__ u2,
                                            const float* __restrict__ stats1,
                                            const float* __restrict__ gamma,
                                            const float* __restrict__ beta,
                                            const unsigned short* __restrict__ w1t,
                                            const float* __restrict__ b1,
                                            const unsigned short* __restrict__ w2t,
                                            const float* __restrict__ b2,
                                            float* __restrict__ v) {
    __shared__ __align__(16) float sscale[DIM], sshift[DIM];
    __shared__ __align__(16) unsigned short y1s[4][16 * 136];   // per-wave, pad 8 shorts/row
    __shared__ __align__(16) unsigned int   hbuf[4][16 * 66];   // per-wave, pad 2 uints/row
    int tid = threadIdx.x;
    if (tid < DIM) {
        float mu  = stats1[tid] * (1.0f / NN);
        float var = stats1[DIM + tid] * (1.0f / NN) - mu * mu;
        float sc = rsqrtf(var + BN_EPS) * gamma[tid];
        sscale[tid] = sc;
        sshift[tid] = beta[tid] - mu * sc;
    }
    __syncthreads();
    int wave = tid >> 6, lane = tid & 63;
    int strip = blockIdx.x * 4 + wave;           // 6250 strips of 16 rows, exact
    if (strip >= NN / 16) return;
    int m = lane & 15, q = lane >> 4;
    unsigned short* y1 = &y1s[wave][0];
    unsigned int*   hb = &hbuf[wave][0];

    // phase A: load u rows (bf16 packed), BN1, store y1 to LDS
    {
        int row = strip * 16 + m;
        const uint4* usrc = (const uint4*)(u2 + (size_t)row * 64 + q * 16);
        #pragma unroll
        for (int g = 0; g < 4; ++g) {
            uint4 pv = usrc[g];
            int c0 = q * 32 + g * 8;
            float4 sc0 = *(const float4*)&sscale[c0], sc1 = *(const float4*)&sscale[c0 + 4];
            float4 sh0 = *(const float4*)&sshift[c0], sh1 = *(const float4*)&sshift[c0 + 4];
            float f0 = __uint_as_float(pv.x << 16)         * sc0.x + sh0.x;
            float f1 = __uint_as_float(pv.x & 0xffff0000u) * sc0.y + sh0.y;
            float f2 = __uint_as_float(pv.y << 16)         * sc0.z + sh0.z;
            float f3 = __uint_as_float(pv.y & 0xffff0000u) * sc0.w + sh0.w;
            float f4 = __uint_as_float(pv.z << 16)         * sc1.x + sh1.x;
            float f5 = __uint_as_float(pv.z & 0xffff0000u) * sc1.y + sh1.y;
            float f6 = __uint_as_float(pv.w << 16)         * sc1.z + sh1.z;
            float f7 = __uint_as_float(pv.w & 0xffff0000u) * sc1.w + sh1.w;
            uint4 ov;
            ov.x = ((unsigned int)f2bfu(f1) << 16) | f2bfu(f0);
            ov.y = ((unsigned int)f2bfu(f3) << 16) | f2bfu(f2);
            ov.z = ((unsigned int)f2bfu(f5) << 16) | f2bfu(f4);
            ov.w = ((unsigned int)f2bfu(f7) << 16) | f2bfu(f6);
            *(uint4*)(y1 + m * 136 + c0) = ov;
        }
    }
    // y1 frags (B-operand for gemm1T; lane&15 = node, k contiguous)
    short8 yfrag[4];
    #pragma unroll
    for (int kt = 0; kt < 4; ++kt)
        yfrag[kt] = *(const short8*)(y1 + m * 136 + kt * 32 + q * 8);

    floatx4 acc2[8];
    #pragma unroll
    for (int t = 0; t < 8; ++t) acc2[t] = (floatx4){0.f, 0.f, 0.f, 0.f};

    #pragma unroll
    for (int c = 0; c < 4; ++c) {
        const unsigned short* w1c = w1t + (size_t)(c * 128) * DIM;
        // gemm1T: D(16 hid x 16 node) = w1t_frag x y1_frag
        floatx4 acc1[8];
        #pragma unroll
        for (int t = 0; t < 8; ++t) acc1[t] = (floatx4){0.f, 0.f, 0.f, 0.f};
        #pragma unroll
        for (int kt = 0; kt < 4; ++kt) {
            #pragma unroll
            for (int t = 0; t < 8; ++t) {
                short8 wf = *(const short8*)(w1c + (size_t)(t * 16 + m) * DIM + kt * 32 + q * 8);
                acc1[t] = __builtin_amdgcn_mfma_f32_16x16x32_bf16(wf, yfrag[kt], acc1[t], 0, 0, 0);
            }
        }
        // relu + bias; lane holds h[node=m][hid = t*16 + q*4 + i] -> pack k-block b = t*4+q
        #pragma unroll
        for (int t = 0; t < 8; ++t) {
            float4 bb = *(const float4*)&b1[c * 128 + t * 16 + q * 4];
            float h0 = fmaxf(acc1[t][0] + bb.x, 0.f);
            float h1 = fmaxf(acc1[t][1] + bb.y, 0.f);
            float h2 = fmaxf(acc1[t][2] + bb.z, 0.f);
            float h3 = fmaxf(acc1[t][3] + bb.w, 0.f);
            uint2 hp;
            hp.x = ((unsigned int)f2bfu(h1) << 16) | f2bfu(h0);
            hp.y = ((unsigned int)f2bfu(h3) << 16) | f2bfu(h2);
            *(uint2*)(hb + m * 66 + (t * 4 + q) * 2) = hp;
        }
        // gemm2: A = h frag (node m, k contiguous via hbuf), B = w2t frag
        const unsigned short* w2c = w2t + c * 128;
        #pragma unroll
        for (int kt = 0; kt < 4; ++kt) {
            uint2 p0 = *(const uint2*)(hb + m * 66 + (8 * kt + 2 * q) * 2);
            uint2 p1 = *(const uint2*)(hb + m * 66 + (8 * kt + 2 * q) * 2 + 2);
            union { unsigned int u[4]; short8 s; } hf;
            hf.u[0] = p0.x; hf.u[1] = p0.y; hf.u[2] = p1.x; hf.u[3] = p1.y;
            #pragma unroll
            for (int t = 0; t < 8; ++t) {
                short8 wf = *(const short8*)(w2c + (size_t)(t * 16 + m) * HID + kt * 32 + q * 8);
                acc2[t] = __builtin_amdgcn_mfma_f32_16x16x32_bf16(hf.s, wf, acc2[t], 0, 0, 0);
            }
        }
    }
    // epilogue: C acc2[t]: node = q*4+i, outcol = t*16+m; v = y1 + ff + b2
    #pragma unroll
    for (int t = 0; t < 8; ++t) {
        float b2c = b2[t * 16 + m];
        #pragma unroll
        for (int i = 0; i < 4; ++i) {
            int r = q * 4 + i;
            float y1v = bfu2f(y1[r * 136 + t * 16 + m]);
            v[(size_t)(strip * 16 + r) * DIM + t * 16 + m] = acc2[t][i] + b2c + y1v;
        }
    }
}

// ---------------- final BN2 in place on v (fp32, in d_out) ----------------
__global__ void k_final(float* buf, const float* __restrict__ stats2,
                        const float* __restrict__ gamma,
                        const float* __restrict__ beta) {
    __shared__ float ssc[DIM], ssh[DIM];
    int t = threadIdx.x;
    if (t < DIM) {
        float mu  = stats2[t] * (1.0f / NN);
        float var = stats2[DIM + t] * (1.0f / NN) - mu * mu;
        float rsg = rsqrtf(var + BN_EPS) * gamma[t];
        ssc[t] = rsg;
        ssh[t] = beta[t] - mu * rsg;
    }
    __syncthreads();
    const int total = NN * DIM / 4;   // float4s
    float4* b4 = (float4*)buf;
    for (int i = blockIdx.x * blockDim.x + t; i < total; i += gridDim.x * blockDim.x) {
        float4 val = b4[i];
        int c = (i * 4) & (DIM - 1);
        val.x = val.x * ssc[c]     + ssh[c];
        val.y = val.y * ssc[c + 1] + ssh[c + 1];
        val.z = val.z * ssc[c + 2] + ssh[c + 2];
        val.w = val.w * ssc[c + 3] + ssh[c + 3];
        b4[i] = val;
    }
}

extern "C" void kernel_launch(void* const* d_in, const int* in_sizes, int n_in,
                              void* d_out, int out_size, void* d_ws, size_t ws_size,
                              hipStream_t stream) {
    const float* x     = (const float*)d_in[0];
    const int*   ei    = (const int*)d_in[1];
    const float* W     = (const float*)d_in[2];
    const float* b     = (const float*)d_in[3];
    const float* gamma = (const float*)d_in[4];
    const float* beta  = (const float*)d_in[5];
    const float* w1    = (const float*)d_in[6];
    const float* b1    = (const float*)d_in[7];
    const float* w2    = (const float*)d_in[8];
    const float* b2    = (const float*)d_in[9];

    // workspace bump allocator (~28 MB), 256B-aligned regions
    char* p = (char*)d_ws;
    auto alloc = [&](size_t bytes) { char* r = p; p += (bytes + 255) & ~(size_t)255; return r; };
    unsigned int*   u     = (unsigned int*)alloc((size_t)NN * DIM * 2);   // u = x + h, bf16 packed
    int*            cnt   = (int*)alloc((size_t)NN * 4);
    int*            offs  = (int*)alloc((size_t)(NN + 1) * 4);
    int*            cur   = (int*)alloc((size_t)NN * 4);
    float*          dinv  = (float*)alloc((size_t)NN * 4);
    int*            bsum  = (int*)alloc(128 * 4);
    unsigned short* wt    = (unsigned short*)alloc((size_t)DIM * DIM * 2);
    unsigned short* w1t   = (unsigned short*)alloc((size_t)HID * DIM * 2);
    unsigned short* w2t   = (unsigned short*)alloc((size_t)HID * DIM * 2);
    float*          stats = (float*)alloc(512 * 4);

    // d_out (51.2 MB fp32) doubles as scratch during the graph phase:
    //   [0, 25.6MB)      xw  (bf16, N*D)
    //   [25.6, 38.4MB)   srcs (int, NE)        — both dead before k_ff writes v
    unsigned short* xw   = (unsigned short*)d_out;
    int*            srcs = (int*)((char*)d_out + (size_t)NN * DIM * 2);
    float*          v    = (float*)d_out;

    const int* esrc = ei;
    const int* edst = ei + NE;
    const int nblk = (NN + 1023) / 1024;   // 98

    k_init<<<(NN + 255) / 256, 256, 0, stream>>>(cnt, stats);
    k_count<<<(NE + 255) / 256, 256, 0, stream>>>(edst, cnt);
    k_scanA<<<nblk, 1024, 0, stream>>>(cnt, offs, bsum, dinv);
    k_scanB<<<1, 128, 0, stream>>>(bsum, offs, nblk);
    k_scanC<<<(NN + 255) / 256, 256, 0, stream>>>(offs, bsum, cur);
    k_fill<<<FILL_GROUPS * 8, 256, 0, stream>>>(esrc, edst, cur, srcs);
    k_wt<<<(DIM * DIM + 255) / 256, 256, 0, stream>>>(W, wt);
    k_prep<<<(HID * DIM + 255) / 256, 256, 0, stream>>>(w1, w2, w1t, w2t);
    k_gemm1<<<(NN + 63) / 64, 256, 0, stream>>>(x, wt, xw);
    k_aggregate<<<(NN + 3) / 4, 256, 0, stream>>>((const unsigned int*)xw, offs, srcs, dinv, x, b, u);
    k_stats<<<512, 256, 0, stream>>>(u, stats);
    k_ff<<<(NN / 16 + 3) / 4, 256, 0, stream>>>(u, stats, gamma, beta, w1t, b1, w2t, b2, v);
    k_stats2<<<512, 256, 0, stream>>>((const float2*)v, stats + 256);
    k_final<<<2048, 256, 0, stream>>>((float*)d_out, stats + 256, gamma, beta);
}

// Round 6
// 809.984 us; speedup vs baseline: 2.0529x; 1.1038x over previous
//
#include <hip/hip_runtime.h>
#include <hip/hip_bf16.h>
#include <stdint.h>

#define NN 100000
#define NE 3200000
#define DIM 128
#define HID 512
#define BN_EPS 1e-5f
#define FILL_GROUPS 128   // k_fill: edge chunks; grid = FILL_GROUPS*8 blocks

typedef short short8 __attribute__((ext_vector_type(8)));
typedef float floatx4 __attribute__((ext_vector_type(4)));

__device__ __forceinline__ float bfu2f(unsigned short u) {
    return __uint_as_float(((unsigned int)u) << 16);
}
__device__ __forceinline__ unsigned short f2bfu(float f) {
    union { __hip_bfloat16 h; unsigned short u; } cv;
    cv.h = __float2bfloat16(f);
    return cv.u;
}

// ---------------- init: zero edge counters + BN stat accumulators ----------------
__global__ void k_init(int* __restrict__ cnt, float* __restrict__ stats) {
    int i = blockIdx.x * 256 + threadIdx.x;
    if (i < NN) cnt[i] = 0;
    if (i < 512) stats[i] = 0.f;   // [0..127]=sum1,[128..255]=sq1,[256..383]=sum2,[384..511]=sq2
}

// ---------------- count incoming edges per dst ----------------
__global__ void k_count(const int* __restrict__ dst, int* __restrict__ cnt) {
    int e = blockIdx.x * 256 + threadIdx.x;
    if (e < NE) atomicAdd(&cnt[dst[e]], 1);
}

// ---------------- scan stage A: per-block (1024-wide) local exclusive scan + block sums + dinv ----
__global__ __launch_bounds__(1024) void k_scanA(const int* __restrict__ cnt, int* __restrict__ offs,
                                                int* __restrict__ bsum, float* __restrict__ dinv) {
    __shared__ int wsum[16];
    int t = threadIdx.x;          // 1024 threads = 16 waves
    int lane = t & 63, wid = t >> 6;
    int i = blockIdx.x * 1024 + t;
    int v = (i < NN) ? cnt[i] : 0;
    int incl = v;
    #pragma unroll
    for (int off = 1; off < 64; off <<= 1) {
        int y = __shfl_up(incl, off, 64);
        if (lane >= off) incl += y;
    }
    if (lane == 63) wsum[wid] = incl;
    __syncthreads();
    if (wid == 0) {
        int wv = (lane < 16) ? wsum[lane] : 0;
        int wincl = wv;
        #pragma unroll
        for (int off = 1; off < 16; off <<= 1) {
            int y = __shfl_up(wincl, off, 64);
            if (lane >= off) wincl += y;
        }
        if (lane < 16) wsum[lane] = wincl - wv;   // exclusive wave offsets
    }
    __syncthreads();
    int excl = wsum[wid] + incl - v;              // block-local exclusive
    if (i < NN) {
        offs[i] = excl;
        dinv[i] = rsqrtf((float)(v + 1));         // deg includes self-loop
    }
    if (t == 1023) bsum[blockIdx.x] = excl + v;   // block total
}

// ---------------- scan stage B: single block scans the 98 block sums ----------------
__global__ __launch_bounds__(128) void k_scanB(int* __restrict__ bsum, int* __restrict__ offs, int nblk) {
    int t = threadIdx.x;   // 128 >= nblk; two waves, use wave 0 only
    if (t < 64) {
        int v = (t < nblk) ? bsum[t] : 0;
        int v2 = (t + 64 < nblk) ? bsum[t + 64] : 0;
        int incl = v;
        #pragma unroll
        for (int off = 1; off < 64; off <<= 1) {
            int y = __shfl_up(incl, off, 64);
            if (t >= off) incl += y;
        }
        int tot0 = __shfl(incl, 63, 64);
        int incl2 = v2;
        #pragma unroll
        for (int off = 1; off < 64; off <<= 1) {
            int y = __shfl_up(incl2, off, 64);
            if (t >= off) incl2 += y;
        }
        if (t < nblk) bsum[t] = incl - v;                      // exclusive
        if (t + 64 < nblk) bsum[t + 64] = tot0 + incl2 - v2;
        if (t == 63) offs[NN] = tot0 + __shfl(incl2, 63, 64);  // grand total
    }
}

// ---------------- scan stage C: add block bases; init cur ----------------
__global__ void k_scanC(int* __restrict__ offs, const int* __restrict__ bsum, int* __restrict__ cur) {
    int i = blockIdx.x * 256 + threadIdx.x;
    if (i < NN) {
        int o = offs[i] + bsum[i >> 10];
        offs[i] = o;
        cur[i] = o;
    }
}

// ---------------- fill CSR src lists, XCD-range-partitioned ----------------
__global__ __launch_bounds__(256) void k_fill(const int* __restrict__ src, const int* __restrict__ dst,
                                              int* __restrict__ cur, int* __restrict__ srcs) {
    int k = blockIdx.x & 7;
    int g = blockIdx.x >> 3;
    const int lo = k * (NN / 8), hi = lo + (NN / 8);    // 12500 each, exact
    const int per = NE / FILL_GROUPS;                    // 25000, exact
    int base = g * per;
    for (int e = base + threadIdx.x; e < base + per; e += 256) {
        int d = dst[e];
        if (d >= lo && d < hi) {
            int p = atomicAdd(&cur[d], 1);
            if ((unsigned)p < NE) srcs[p] = src[e];
        }
    }
}

// ---------------- transpose W (fp32) -> bf16 wt[n][k] ----------------
__global__ void k_wt(const float* __restrict__ W, unsigned short* __restrict__ wt) {
    int i = blockIdx.x * 256 + threadIdx.x;
    if (i < DIM * DIM) {
        int k = i >> 7, n = i & 127;
        wt[n * DIM + k] = f2bfu(W[k * DIM + n]);
    }
}

// ---------------- prep FF weights: w1t[n=512][k=128], w2t[n=128][k=512] (bf16, transposed) -------
__global__ void k_prep(const float* __restrict__ w1, const float* __restrict__ w2,
                       unsigned short* __restrict__ w1t, unsigned short* __restrict__ w2t) {
    int i = blockIdx.x * 256 + threadIdx.x;
    if (i < HID * DIM) {
        int n1 = i >> 7, k1 = i & 127;           // w1t[n1*128+k1] = w1[k1*512+n1]
        w1t[i] = f2bfu(w1[k1 * HID + n1]);
        int n2 = i & 127, k2 = i >> 7;           // w2t[n2*512+k2] = w2[k2*DIM+n2]
        w2t[n2 * HID + k2] = f2bfu(w2[k2 * DIM + n2]);
    }
}

// ---------------- xw = bf16(x) @ bf16(W) via MFMA 16x16x32; xw bf16 (lives in d_out) ----------------
__global__ __launch_bounds__(256) void k_gemm1(const float* __restrict__ x,
                                               const unsigned short* __restrict__ wt,
                                               unsigned short* __restrict__ xw) {
    int wave = threadIdx.x >> 6;
    int lane = threadIdx.x & 63;
    int row0 = blockIdx.x * 64 + wave * 16;
    int arow = row0 + (lane & 15);
    if (arow >= NN) arow = NN - 1;        // clamp; stores are guarded
    int kbase = (lane >> 4) * 8;
    const float* xr = x + (size_t)arow * DIM;
    short8 afrag[4];
    #pragma unroll
    for (int kt = 0; kt < 4; ++kt) {
        float4 f0 = *(const float4*)(xr + kt * 32 + kbase);
        float4 f1 = *(const float4*)(xr + kt * 32 + kbase + 4);
        short8 a;
        a[0] = (short)f2bfu(f0.x); a[1] = (short)f2bfu(f0.y);
        a[2] = (short)f2bfu(f0.z); a[3] = (short)f2bfu(f0.w);
        a[4] = (short)f2bfu(f1.x); a[5] = (short)f2bfu(f1.y);
        a[6] = (short)f2bfu(f1.z); a[7] = (short)f2bfu(f1.w);
        afrag[kt] = a;                     // A[m=lane&15][k=quad*8+j]
    }
    int crow = row0 + (lane >> 4) * 4;
    #pragma unroll
    for (int ct = 0; ct < 8; ++ct) {
        int ncol = ct * 16 + (lane & 15);
        const short* wr = (const short*)wt + (size_t)ncol * DIM;
        floatx4 acc = {0.f, 0.f, 0.f, 0.f};
        #pragma unroll
        for (int kt = 0; kt < 4; ++kt) {
            short8 bfrag = *(const short8*)(wr + kt * 32 + kbase); // B[k=quad*8+j][n=lane&15]
            acc = __builtin_amdgcn_mfma_f32_16x16x32_bf16(afrag[kt], bfrag, acc, 0, 0, 0);
        }
        #pragma unroll
        for (int i = 0; i < 4; ++i) {
            int r = crow + i;                  // C: row=(lane>>4)*4+reg, col=lane&15
            if (r < NN) xw[(size_t)r * DIM + ct * 16 + (lane & 15)] = f2bfu(acc[i]);
        }
    }
}

// ---------------- per-node wave: u = bf16(x + h), h = sym-norm aggregate + bias ----------------
__global__ __launch_bounds__(256) void k_aggregate(const unsigned int* __restrict__ xw2,
                                                   const int* __restrict__ offs,
                                                   const int* __restrict__ srcs,
                                                   const float* __restrict__ dinv,
                                                   const float* __restrict__ x,
                                                   const float* __restrict__ b,
                                                   unsigned int* __restrict__ u) {
    int node = blockIdx.x * 4 + (threadIdx.x >> 6);
    if (node >= NN) return;
    int lane = threadIdx.x & 63;               // lane handles cols 2*lane, 2*lane+1
    int beg = offs[node], end = offs[node + 1];
    beg = max(0, min(beg, NE));
    end = max(beg, min(end, NE));
    float a0 = 0.f, a1 = 0.f;
    #pragma unroll 4
    for (int e = beg; e < end; ++e) {
        int s = srcs[e];
        if ((unsigned)s >= NN) s = 0;
        float w = dinv[s];
        unsigned int pw = xw2[(size_t)s * (DIM / 2) + lane];
        a0 = fmaf(w, __uint_as_float(pw << 16), a0);
        a1 = fmaf(w, __uint_as_float(pw & 0xffff0000u), a1);
    }
    float di = dinv[node];
    unsigned int ps = xw2[(size_t)node * (DIM / 2) + lane];
    a0 = di * a0 + di * di * __uint_as_float(ps << 16);
    a1 = di * a1 + di * di * __uint_as_float(ps & 0xffff0000u);
    float2 xv = ((const float2*)x)[(size_t)node * (DIM / 2) + lane];
    float2 bv = ((const float2*)b)[lane];
    float o0 = a0 + bv.x + xv.x;
    float o1 = a1 + bv.y + xv.y;
    unsigned int pk = ((unsigned int)f2bfu(o1) << 16) | (unsigned int)f2bfu(o0);
    u[(size_t)node * (DIM / 2) + lane] = pk;
}

// ---------------- BN1 stats: per-column sum & sumsq of u (bf16) ----------------
__global__ void k_stats(const unsigned int* __restrict__ u2, float* __restrict__ stats) {
    int t = threadIdx.x;            // 256
    int c = t & 63, g = t >> 6;     // uint index c -> bf16 cols 2c, 2c+1
    float s0 = 0.f, q0 = 0.f, s1 = 0.f, q1 = 0.f;
    for (int r = blockIdx.x * 4 + g; r < NN; r += gridDim.x * 4) {
        unsigned int pv = u2[(size_t)r * 64 + c];
        float x0 = __uint_as_float(pv << 16);
        float x1 = __uint_as_float(pv & 0xffff0000u);
        s0 += x0; q0 += x0 * x0; s1 += x1; q1 += x1 * x1;
    }
    __shared__ float A[256], B[256], C[256], D2[256];
    A[t] = s0; B[t] = q0; C[t] = s1; D2[t] = q1;
    __syncthreads();
    if (t < 64) {
        float rs0 = A[t] + A[t + 64] + A[t + 128] + A[t + 192];
        float rq0 = B[t] + B[t + 64] + B[t + 128] + B[t + 192];
        float rs1 = C[t] + C[t + 64] + C[t + 128] + C[t + 192];
        float rq1 = D2[t] + D2[t + 64] + D2[t + 128] + D2[t + 192];
        atomicAdd(&stats[2 * c],           rs0);
        atomicAdd(&stats[2 * c + 1],       rs1);
        atomicAdd(&stats[DIM + 2 * c],     rq0);
        atomicAdd(&stats[DIM + 2 * c + 1], rq1);
    }
}

// ---------------- BN2 stats: per-column sum & sumsq of v (fp32) ----------------
__global__ void k_stats2(const float2* __restrict__ v2, float* __restrict__ stats) {
    int t = threadIdx.x;            // 256
    int c = t & 63, g = t >> 6;     // float2 index c -> cols 2c, 2c+1
    float s0 = 0.f, q0 = 0.f, s1 = 0.f, q1 = 0.f;
    for (int r = blockIdx.x * 4 + g; r < NN; r += gridDim.x * 4) {
        float2 pv = v2[(size_t)r * 64 + c];
        s0 += pv.x; q0 += pv.x * pv.x; s1 += pv.y; q1 += pv.y * pv.y;
    }
    __shared__ float A[256], B[256], C[256], D2[256];
    A[t] = s0; B[t] = q0; C[t] = s1; D2[t] = q1;
    __syncthreads();
    if (t < 64) {
        float rs0 = A[t] + A[t + 64] + A[t + 128] + A[t + 192];
        float rq0 = B[t] + B[t + 64] + B[t + 128] + B[t + 192];
        float rs1 = C[t] + C[t + 64] + C[t + 128] + C[t + 192];
        float rq1 = D2[t] + D2[t + 64] + D2[t + 128] + D2[t + 192];
        atomicAdd(&stats[2 * c],           rs0);
        atomicAdd(&stats[2 * c + 1],       rs1);
        atomicAdd(&stats[DIM + 2 * c],     rq0);
        atomicAdd(&stats[DIM + 2 * c + 1], rq1);
    }
}

// ---------------- fused FF v2: weights LDS-staged per 64-hid chunk, 128 nodes/block ----------------
// Block: 4 waves x 32 nodes (2 strips of 16). Loop c=0..7 over 64-hid chunks:
//   stage w1c [64 hid][128 k] (16KB) + w2c [128 out][64 k] (16KB) into LDS (XOR-swizzled rows,
//   conflict-free b128 frag reads), gemm1T -> relu -> hbuf(LDS) -> gemm2 accumulating acc2 in regs.
// yfrags (BN1(u)) built once from global u; epilogue recomputes y1 residual from u + scale/shift.
__global__ __launch_bounds__(256) void k_ffx(const unsigned int* __restrict__ u2,
                                             const float* __restrict__ stats1,
                                             const float* __restrict__ gamma,
                                             const float* __restrict__ beta,
                                             const unsigned short* __restrict__ w1t,
                                             const float* __restrict__ b1,
                                             const unsigned short* __restrict__ w2t,
                                             const float* __restrict__ b2,
                                             float* __restrict__ v) {
    __shared__ __align__(16) float sscale[DIM], sshift[DIM];
    __shared__ __align__(16) unsigned int sw1[64 * 64];       // 16KB: w1 chunk [64 hid][128 k bf16]
    __shared__ __align__(16) unsigned int sw2[128 * 32];      // 16KB: w2 chunk [128 out][64 k bf16]
    __shared__ __align__(16) unsigned int hbufs[4][16 * 32];  // 8KB: per-wave h strip [16 node][64 hid]
    int tid = threadIdx.x;
    if (tid < DIM) {
        float mu  = stats1[tid] * (1.0f / NN);
        float var = stats1[DIM + tid] * (1.0f / NN) - mu * mu;
        float sc = rsqrtf(var + BN_EPS) * gamma[tid];
        sscale[tid] = sc;
        sshift[tid] = beta[tid] - mu * sc;
    }
    __syncthreads();
    int wave = tid >> 6, lane = tid & 63;
    int m = lane & 15, q = lane >> 4;
    int nb = blockIdx.x * 128 + wave * 32;       // this wave's 32 nodes
    unsigned int* hb = &hbufs[wave][0];
    const int xsw = (m & 7) * 4;                 // per-lane XOR swizzle (dwords)

    // build yfrags: y1 = BN1(u) for this wave's 2 strips, direct from global
    short8 yfrag[2][4];
    #pragma unroll
    for (int s = 0; s < 2; ++s) {
        int ng = nb + s * 16 + m;
        if (ng >= NN) ng = NN - 1;
        const uint4* up = (const uint4*)(u2 + (size_t)ng * 64);
        #pragma unroll
        for (int kt = 0; kt < 4; ++kt) {
            uint4 pv = up[kt * 4 + q];
            int c0 = kt * 32 + q * 8;
            float4 sa = *(const float4*)&sscale[c0], sb = *(const float4*)&sscale[c0 + 4];
            float4 ha = *(const float4*)&sshift[c0], hbv = *(const float4*)&sshift[c0 + 4];
            float f0 = __uint_as_float(pv.x << 16)         * sa.x + ha.x;
            float f1 = __uint_as_float(pv.x & 0xffff0000u) * sa.y + ha.y;
            float f2 = __uint_as_float(pv.y << 16)         * sa.z + ha.z;
            float f3 = __uint_as_float(pv.y & 0xffff0000u) * sa.w + ha.w;
            float f4 = __uint_as_float(pv.z << 16)         * sb.x + hbv.x;
            float f5 = __uint_as_float(pv.z & 0xffff0000u) * sb.y + hbv.y;
            float f6 = __uint_as_float(pv.w << 16)         * sb.z + hbv.z;
            float f7 = __uint_as_float(pv.w & 0xffff0000u) * sb.w + hbv.w;
            union { unsigned int u[4]; short8 sv; } yf;
            yf.u[0] = ((unsigned int)f2bfu(f1) << 16) | f2bfu(f0);
            yf.u[1] = ((unsigned int)f2bfu(f3) << 16) | f2bfu(f2);
            yf.u[2] = ((unsigned int)f2bfu(f5) << 16) | f2bfu(f4);
            yf.u[3] = ((unsigned int)f2bfu(f7) << 16) | f2bfu(f6);
            yfrag[s][kt] = yf.sv;
        }
    }

    floatx4 acc2[2][8];
    #pragma unroll
    for (int s = 0; s < 2; ++s)
        #pragma unroll
        for (int t = 0; t < 8; ++t) acc2[s][t] = (floatx4){0.f, 0.f, 0.f, 0.f};

    const uint4* w1g = (const uint4*)w1t;   // row n: 16 uint4
    const uint4* w2g = (const uint4*)w2t;   // row n: 64 uint4

    for (int c = 0; c < 8; ++c) {
        __syncthreads();                     // protect sw from previous iteration's readers
        #pragma unroll
        for (int it = 0; it < 4; ++it) {     // stage w1c: 64 rows x 16 uint4
            int i = tid + it * 256;
            int j = i >> 4, s4 = i & 15;
            uint4 val = w1g[(size_t)(c * 64 + j) * 16 + s4];
            *(uint4*)&sw1[j * 64 + ((s4 * 4) ^ ((j & 7) * 4))] = val;
        }
        #pragma unroll
        for (int it = 0; it < 4; ++it) {     // stage w2c: 128 rows x 8 uint4 (k-window c*64)
            int i = tid + it * 256;
            int n = i >> 3, s4 = i & 7;
            uint4 val = w2g[(size_t)n * 64 + c * 8 + s4];
            *(uint4*)&sw2[n * 32 + ((s4 * 4) ^ ((n & 7) * 4))] = val;
        }
        __syncthreads();
        #pragma unroll
        for (int s = 0; s < 2; ++s) {
            // gemm1T: h^T(64 hid x 16 node) for this strip
            floatx4 acc1[4];
            #pragma unroll
            for (int t = 0; t < 4; ++t) acc1[t] = (floatx4){0.f, 0.f, 0.f, 0.f};
            #pragma unroll
            for (int kt = 0; kt < 4; ++kt) {
                #pragma unroll
                for (int t = 0; t < 4; ++t) {
                    short8 wf = *(const short8*)&sw1[(t * 16 + m) * 64 + ((kt * 16 + q * 4) ^ xsw)];
                    acc1[t] = __builtin_amdgcn_mfma_f32_16x16x32_bf16(wf, yfrag[s][kt], acc1[t], 0, 0, 0);
                }
            }
            // relu + bias -> hbuf (lane holds h[node=m][hid=c*64 + t*16 + q*4 + i])
            #pragma unroll
            for (int t = 0; t < 4; ++t) {
                float4 bb = *(const float4*)&b1[c * 64 + t * 16 + q * 4];
                float h0 = fmaxf(acc1[t][0] + bb.x, 0.f);
                float h1 = fmaxf(acc1[t][1] + bb.y, 0.f);
                float h2 = fmaxf(acc1[t][2] + bb.z, 0.f);
                float h3 = fmaxf(acc1[t][3] + bb.w, 0.f);
                uint2 hp;
                hp.x = ((unsigned int)f2bfu(h1) << 16) | f2bfu(h0);
                hp.y = ((unsigned int)f2bfu(h3) << 16) | f2bfu(h2);
                *(uint2*)&hb[m * 32 + ((t * 8 + q * 2) ^ xsw)] = hp;
            }
            // gemm2: acc2 += h(16 node x 64 k) x w2c(64 k x 128 out)
            #pragma unroll
            for (int kt = 0; kt < 2; ++kt) {
                short8 hf = *(const short8*)&hb[m * 32 + ((kt * 16 + q * 4) ^ xsw)];
                #pragma unroll
                for (int t = 0; t < 8; ++t) {
                    short8 wf2 = *(const short8*)&sw2[(t * 16 + m) * 32 + ((kt * 16 + q * 4) ^ xsw)];
                    acc2[s][t] = __builtin_amdgcn_mfma_f32_16x16x32_bf16(hf, wf2, acc2[s][t], 0, 0, 0);
                }
            }
        }
    }
    // epilogue: C acc2[s][t]: node = q*4+i, outcol = t*16+m; v = y1 + ff + b2
    #pragma unroll
    for (int s = 0; s < 2; ++s) {
        #pragma unroll
        for (int t = 0; t < 8; ++t) {
            int col = t * 16 + m;
            float b2v = b2[col];
            float scl = sscale[col], shf = sshift[col];
            #pragma unroll
            for (int i = 0; i < 4; ++i) {
                int ng = nb + s * 16 + q * 4 + i;
                if (ng < NN) {
                    unsigned int pv = u2[(size_t)ng * 64 + (col >> 1)];
                    float uval = (col & 1) ? __uint_as_float(pv & 0xffff0000u)
                                           : __uint_as_float(pv << 16);
                    v[(size_t)ng * DIM + col] = acc2[s][t][i] + b2v + (uval * scl + shf);
                }
            }
        }
    }
}

// ---------------- final BN2 in place on v (fp32, in d_out) ----------------
__global__ void k_final(float* buf, const float* __restrict__ stats2,
                        const float* __restrict__ gamma,
                        const float* __restrict__ beta) {
    __shared__ float ssc[DIM], ssh[DIM];
    int t = threadIdx.x;
    if (t < DIM) {
        float mu  = stats2[t] * (1.0f / NN);
        float var = stats2[DIM + t] * (1.0f / NN) - mu * mu;
        float rsg = rsqrtf(var + BN_EPS) * gamma[t];
        ssc[t] = rsg;
        ssh[t] = beta[t] - mu * rsg;
    }
    __syncthreads();
    const int total = NN * DIM / 4;   // float4s
    float4* b4 = (float4*)buf;
    for (int i = blockIdx.x * blockDim.x + t; i < total; i += gridDim.x * blockDim.x) {
        float4 val = b4[i];
        int c = (i * 4) & (DIM - 1);
        val.x = val.x * ssc[c]     + ssh[c];
        val.y = val.y * ssc[c + 1] + ssh[c + 1];
        val.z = val.z * ssc[c + 2] + ssh[c + 2];
        val.w = val.w * ssc[c + 3] + ssh[c + 3];
        b4[i] = val;
    }
}

extern "C" void kernel_launch(void* const* d_in, const int* in_sizes, int n_in,
                              void* d_out, int out_size, void* d_ws, size_t ws_size,
                              hipStream_t stream) {
    const float* x     = (const float*)d_in[0];
    const int*   ei    = (const int*)d_in[1];
    const float* W     = (const float*)d_in[2];
    const float* b     = (const float*)d_in[3];
    const float* gamma = (const float*)d_in[4];
    const float* beta  = (const float*)d_in[5];
    const float* w1    = (const float*)d_in[6];
    const float* b1    = (const float*)d_in[7];
    const float* w2    = (const float*)d_in[8];
    const float* b2    = (const float*)d_in[9];

    // workspace bump allocator (~28 MB), 256B-aligned regions
    char* p = (char*)d_ws;
    auto alloc = [&](size_t bytes) { char* r = p; p += (bytes + 255) & ~(size_t)255; return r; };
    unsigned int*   u     = (unsigned int*)alloc((size_t)NN * DIM * 2);   // u = x + h, bf16 packed
    int*            cnt   = (int*)alloc((size_t)NN * 4);
    int*            offs  = (int*)alloc((size_t)(NN + 1) * 4);
    int*            cur   = (int*)alloc((size_t)NN * 4);
    float*          dinv  = (float*)alloc((size_t)NN * 4);
    int*            bsum  = (int*)alloc(128 * 4);
    unsigned short* wt    = (unsigned short*)alloc((size_t)DIM * DIM * 2);
    unsigned short* w1t   = (unsigned short*)alloc((size_t)HID * DIM * 2);
    unsigned short* w2t   = (unsigned short*)alloc((size_t)HID * DIM * 2);
    float*          stats = (float*)alloc(512 * 4);

    // d_out (51.2 MB fp32) doubles as scratch during the graph phase:
    //   [0, 25.6MB)      xw  (bf16, N*D)
    //   [25.6, 38.4MB)   srcs (int, NE)        — both dead before k_ffx writes v
    unsigned short* xw   = (unsigned short*)d_out;
    int*            srcs = (int*)((char*)d_out + (size_t)NN * DIM * 2);
    float*          v    = (float*)d_out;

    const int* esrc = ei;
    const int* edst = ei + NE;
    const int nblk = (NN + 1023) / 1024;   // 98

    k_init<<<(NN + 255) / 256, 256, 0, stream>>>(cnt, stats);
    k_count<<<(NE + 255) / 256, 256, 0, stream>>>(edst, cnt);
    k_scanA<<<nblk, 1024, 0, stream>>>(cnt, offs, bsum, dinv);
    k_scanB<<<1, 128, 0, stream>>>(bsum, offs, nblk);
    k_scanC<<<(NN + 255) / 256, 256, 0, stream>>>(offs, bsum, cur);
    k_fill<<<FILL_GROUPS * 8, 256, 0, stream>>>(esrc, edst, cur, srcs);
    k_wt<<<(DIM * DIM + 255) / 256, 256, 0, stream>>>(W, wt);
    k_prep<<<(HID * DIM + 255) / 256, 256, 0, stream>>>(w1, w2, w1t, w2t);
    k_gemm1<<<(NN + 63) / 64, 256, 0, stream>>>(x, wt, xw);
    k_aggregate<<<(NN + 3) / 4, 256, 0, stream>>>((const unsigned int*)xw, offs, srcs, dinv, x, b, u);
    k_stats<<<512, 256, 0, stream>>>(u, stats);
    k_ffx<<<(NN + 127) / 128, 256, 0, stream>>>(u, stats, gamma, beta, w1t, b1, w2t, b2, v);
    k_stats2<<<512, 256, 0, stream>>>((const float2*)v, stats + 256);
    k_final<<<2048, 256, 0, stream>>>((float*)d_out, stats + 256, gamma, beta);
}